// Round 12
// baseline (426.494 us; speedup 1.0000x reference)
//
#include <hip/hip_runtime.h>
#include <hip/hip_bf16.h>

#define BB 2
#define NN 256
#define HID 256
#define NH 8
#define HD 32
#define NPAIR (BB*NN*NN)   // 131072

typedef __attribute__((ext_vector_type(8))) short bf16x8;
typedef __attribute__((ext_vector_type(4))) float f32x4;

__device__ __forceinline__ unsigned short f2bf(float f){
  union{float f; unsigned int i;} v; v.f=f;
  unsigned int r = v.i + 0x7fffu + ((v.i>>16)&1u);
  return (unsigned short)(r>>16);
}

__device__ __forceinline__ float block_reduce_sum(float v, float* red){
  int t = threadIdx.x;
  red[t]=v; __syncthreads();
  for(int off=128; off>0; off>>=1){ if(t<off) red[t]+=red[t+off]; __syncthreads(); }
  float r = red[0]; __syncthreads();
  return r;
}

// ---------------------------------------------------------------------------
// K0: reordered bf16 weight WcatT[vcol][k] + bias bcat[vcol] (f32).
// Also zero-inits am (512 x 256 == NPAIR) for k_attn's atomic head-mean.
__global__ void k_build_w(const float* __restrict__ Wep,
                          const float* __restrict__ bep,
                          const float* __restrict__ Weg,
                          const float* __restrict__ beg,
                          unsigned short* __restrict__ WcatT,
                          float* __restrict__ bcat,
                          float* __restrict__ am){
  int vcol = blockIdx.x, k = threadIdx.x;
  am[(size_t)vcol*256 + k] = 0.f;
  int hv = vcol >> 6, wi = vcol & 63;
  int col = hv*32 + (wi & 31);
  const float* W = (wi < 32) ? Wep : Weg;
  WcatT[(size_t)vcol*256 + k] = f2bf(W[(size_t)k*256 + col]);
  if (k==0){
    const float* bb = (wi<32) ? bep : beg;
    bcat[vcol] = bb[col];
  }
}

// ---------------------------------------------------------------------------
// KF: FUSED nodeqkv + edge_gemm. R12: Bs LDS stage DELETED — B frags read
// direct from L2 (WcatT 256KB L2-resident; read path correctness-verified in
// R7). LDS 38.4->20KB raises blocks/CU 4->6 (VGPR-bound at ~84). MLP theory:
// the 2-barrier loop issues loads as a burst then stalls (HBM active ~12%);
// 2.5x more de-phased blocks/CU keeps the HBM pipe fed. A-staging, cvt, MFMA
// order, B values all bitwise-identical to R11.
__global__ __launch_bounds__(256) void k_gemm_qkv(
    const float* __restrict__ edge,            // [NPAIR][256] fp32
    const unsigned short* __restrict__ WcatT,  // [512][256] bf16
    const float* __restrict__ bcat,            // [512]
    float* __restrict__ edge_attn,             // [B*H][N*N]
    const float* __restrict__ node, const float* __restrict__ Wn,
    const float* __restrict__ bn,
    const float* __restrict__ Wq, const float* __restrict__ bq,
    const float* __restrict__ Wk, const float* __restrict__ bk,
    const float* __restrict__ Wv, const float* __restrict__ bv,
    float* __restrict__ h,
    float* __restrict__ Q, float* __restrict__ K, float* __restrict__ V)
{
  __shared__ __align__(16) short As[128][72];
  __shared__ float xs[128];
  __shared__ float hs[256];

  if (blockIdx.x < 1536){
    // ---- nodeqkv body (R10-exact): row x mat, bitwise-identical chains ----
    int row = blockIdx.x & 511, mat = blockIdx.x >> 9, c = threadIdx.x;
    if (c < 128) xs[c] = node[(size_t)row*128 + c];
    __syncthreads();
    float acc = bn[c];
#pragma unroll 16
    for (int k=0;k<128;k++) acc += xs[k]*Wn[(size_t)k*256+c];
    if (mat==0) h[(size_t)row*256+c] = acc;
    hs[c] = acc;
    __syncthreads();
    const float* W  = (mat==0)?Wq:((mat==1)?Wk:Wv);
    const float* bb = (mat==0)?bq:((mat==1)?bk:bv);
    float*       O  = (mat==0)?Q :((mat==1)?K :V );
    float a2 = bb[c];
#pragma unroll 16
    for (int k=0;k<256;k++) a2 += hs[k]*W[(size_t)k*256+c];
    O[(size_t)row*256+c] = a2;
    return;
  }

  // ---- gemm body: A staged+cvt in LDS (R6-exact), B direct from L2 ----
  int id = blockIdx.x - 1536;
  int bm = ((id>>5)<<3) | (id&7);
  int bv2 = (id>>3)&3;
  int tid = threadIdx.x;
  int w = tid>>6, lane = tid&63;
  int wr = w>>1, wc = w&1;
  int q = lane>>4, cl = lane&15;

  f32x4 acc[4][4];
#pragma unroll
  for(int i=0;i<4;i++)
#pragma unroll
    for(int j=0;j<4;j++) acc[i][j] = (f32x4){0.f,0.f,0.f,0.f};

  int r0 = tid>>4, c4 = tid&15;
  const unsigned short* bP = WcatT + (size_t)(bv2*128 + wc*64 + cl)*256;

  for(int kc=0;kc<4;kc++){
    int k0 = kc*64;
#pragma unroll
    for(int i=0;i<8;i++){
      int r = r0 + i*16;
      float4 f = *(const float4*)(edge + (size_t)(bm*128+r)*256 + k0 + c4*4);
      __hip_bfloat162 lo = __float22bfloat162_rn(make_float2(f.x,f.y));
      __hip_bfloat162 hi = __float22bfloat162_rn(make_float2(f.z,f.w));
      uint2 u; u.x = *(unsigned int*)&lo; u.y = *(unsigned int*)&hi;
      *(uint2*)(&As[r][c4*4]) = u;
    }
    __syncthreads();
#pragma unroll
    for(int ks=0;ks<2;ks++){
      int kb = ks*32 + q*8;
      bf16x8 a[4], bfr[4];
#pragma unroll
      for(int tm=0;tm<4;tm++) a[tm]  = *(const bf16x8*)(&As[wr*64+tm*16+cl][kb]);
#pragma unroll
      for(int tn=0;tn<4;tn++) bfr[tn]= *(const bf16x8*)(bP + (size_t)tn*4096 + k0 + kb);
#pragma unroll
      for(int tm=0;tm<4;tm++)
#pragma unroll
        for(int tn=0;tn<4;tn++)
          acc[tm][tn] = __builtin_amdgcn_mfma_f32_16x16x32_bf16(a[tm], bfr[tn], acc[tm][tn], 0, 0, 0);
    }
    __syncthreads();
  }

  int head = bv2*2 + wc;
  float bias[4];
#pragma unroll
  for(int tn=0;tn<4;tn++) bias[tn] = bcat[bv2*128 + wc*64 + tn*16 + cl];

#pragma unroll
  for(int tm=0;tm<4;tm++){
    float s[4] = {0.f,0.f,0.f,0.f};
#pragma unroll
    for(int tn=0;tn<2;tn++){
#pragma unroll
      for(int r=0;r<4;r++){
        float eh = acc[tm][tn][r]   + bias[tn];
        float gg = acc[tm][tn+2][r] + bias[tn+2];
        s[r] += eh * (1.f/(1.f + __expf(-gg)));
      }
    }
#pragma unroll
    for(int off=1;off<16;off<<=1){
#pragma unroll
      for(int r=0;r<4;r++) s[r] += __shfl_xor(s[r], off);
    }
    if (cl==0){
      int R = bm*128 + wr*64 + tm*16 + q*4;
      int b = R>>16, rem = R&65535;
#pragma unroll
      for(int r=0;r<4;r++)
        edge_attn[(size_t)(b*NH+head)*65536 + rem + r] = s[r];
    }
  }
}

// ---------------------------------------------------------------------------
// KC: attention. R12: pad back to 33 — bank analysis: QK reads at pad 33 hit
// bank m%32 (conflict-free); pad 36 hit 4m%32 (8-way). R10's 36 was the null.
// Block stages K/V once, 8 query rows (2 reps x 4 waves); atomic head-mean.
__global__ __launch_bounds__(256) void k_attn(
    const float* __restrict__ Q, const float* __restrict__ Km,
    const float* __restrict__ V, const int* __restrict__ adj,
    float* __restrict__ attn, float* __restrict__ attn_out,
    float* __restrict__ am){
  __shared__ float Ks[256][33];
  __shared__ float Vs[256][33];
  __shared__ float arow[4][264];
  int b = blockIdx.z, hh = blockIdx.y;
  int t = threadIdx.x;
  int mrow = t>>3, dg = (t&7)*4;
#pragma unroll
  for(int it=0; it<8; it++){
    int m = mrow + it*32;
    size_t base = ((size_t)(b*NN+m))*HID + hh*HD + dg;
    *(float4*)&Ks[m][dg] = *(const float4*)(Km + base);
    *(float4*)&Vs[m][dg] = *(const float4*)(V + base);
  }
  __syncthreads();

  int w = t>>6, lane = t&63;
  int mc = lane>>3, dg4 = (lane&7)*4;

  for (int rep=0; rep<2; ++rep){
    int n = blockIdx.x*8 + rep*4 + w;
    const float* qp = Q + ((size_t)(b*NN+n))*HID + hh*HD;
    float4 q[8];
#pragma unroll
    for(int i=0;i<8;i++) q[i] = *(const float4*)(qp + i*4);

    size_t eoff = ((size_t)((b*NH+hh)*NN + n))*NN;
    const int* abase = adj + ((size_t)(b*NN+n))*NN;
    float sc[4];
#pragma unroll
    for(int j=0;j<4;j++){
      int m = lane + j*64;
      float d = 0.f;
#pragma unroll
      for(int i=0;i<8;i++){
        float4 kk = *(float4*)&Ks[m][i*4];
        d += q[i].x*kk.x + q[i].y*kk.y + q[i].z*kk.z + q[i].w*kk.w;
      }
      float s = d*0.17677669529663687f + attn[eoff + m];
      if (abase[m]==0) s = -1e9f;
      sc[j] = s;
    }
    float mx = fmaxf(fmaxf(sc[0],sc[1]),fmaxf(sc[2],sc[3]));
#pragma unroll
    for(int off=1;off<64;off<<=1) mx = fmaxf(mx, __shfl_xor(mx, off));
    float e[4], sum = 0.f;
#pragma unroll
    for(int j=0;j<4;j++){ e[j] = __expf(sc[j]-mx); sum += e[j]; }
#pragma unroll
    for(int off=1;off<64;off<<=1) sum += __shfl_xor(sum, off);
    float inv = 1.f/sum;
    float* amrow = am + (size_t)b*65536 + n*256;
#pragma unroll
    for(int j=0;j<4;j++){
      int m = lane + j*64;
      float a = e[j]*inv;
      attn[eoff + m] = a;
      arow[w][m + (m>>5)] = a;   // stride-33 chunks: conflict-free broadcast
      atomicAdd(amrow + m, a*0.125f);
    }
    float4 o = {0.f,0.f,0.f,0.f};
#pragma unroll
    for(int j=0;j<32;j++){
      int m = mc*32 + j;
      float a = arow[w][m + (m>>5)];
      float4 v = *(float4*)&Vs[m][dg4];
      o.x += a*v.x; o.y += a*v.y; o.z += a*v.z; o.w += a*v.w;
    }
#pragma unroll
    for(int off=8; off<64; off<<=1){
      o.x += __shfl_xor(o.x, off); o.y += __shfl_xor(o.y, off);
      o.z += __shfl_xor(o.z, off); o.w += __shfl_xor(o.w, off);
    }
    if (mc==0)
      *(float4*)(attn_out + ((size_t)(b*NN+n))*HID + hh*HD + dg4) = o;
  }
}

// ---------------------------------------------------------------------------
// KD: fused h_out = LN(h + attn_out@Wo + bo) -> d_out ; P = h_out@Weo
__global__ __launch_bounds__(256) void k_hout(
    const float* __restrict__ attn_out, const float* __restrict__ hres,
    const float* __restrict__ Wo, const float* __restrict__ bo,
    const float* __restrict__ g1, const float* __restrict__ b1,
    const float* __restrict__ Weo,
    float* __restrict__ P, float* __restrict__ out){
  __shared__ float xs[256]; __shared__ float red[256]; __shared__ float hs[256];
  int row = blockIdx.x, c = threadIdx.x;
  xs[c] = attn_out[(size_t)row*256 + c];
  __syncthreads();
  float acc = bo[c];
#pragma unroll 16
  for(int k=0;k<256;k++) acc += xs[k]*Wo[(size_t)k*256+c];
  float val = hres[(size_t)row*256+c] + acc;
  float mean = block_reduce_sum(val, red) * (1.f/256.f);
  float ctr = val - mean;
  float var = block_reduce_sum(ctr*ctr, red) * (1.f/256.f);
  float o = ctr * rsqrtf(var + 1e-5f) * g1[c] + b1[c];
  out[(size_t)row*256+c] = o;
  hs[c] = o;
  __syncthreads();
  float accP = 0.f;
#pragma unroll 16
  for(int k=0;k<256;k++) accP += hs[k]*Weo[(size_t)k*256+c];
  P[(size_t)row*256+c] = accP;
}

// ---------------------------------------------------------------------------
// KE: edge_out = LN(edge + attn_mean*0.5*(P[n]+P[m]) + beo). One wave per pair.
__global__ __launch_bounds__(256) void k_edge_out(
    const float* __restrict__ ef, const float* __restrict__ am,
    const float* __restrict__ P, const float* __restrict__ beo,
    const float* __restrict__ g2, const float* __restrict__ b2,
    float* __restrict__ out){
  int w = threadIdx.x>>6, lane = threadIdx.x&63;
  size_t pair = (size_t)blockIdx.x*4 + w;
  int b = (int)(pair>>16); int rem = (int)(pair&65535);
  int n = rem>>8, m = rem&255;
  float a = am[pair]*0.5f;
  const float* Pn = P + (size_t)(b*NN+n)*HID;
  const float* Pm = P + (size_t)(b*NN+m)*HID;
  int c0 = lane*4;
  float4 ev = *(const float4*)(ef + pair*256 + c0);
  float4 pn = *(const float4*)(Pn + c0);
  float4 pm = *(const float4*)(Pm + c0);
  float4 bo4 = *(const float4*)(beo + c0);
  float v0 = ev.x + a*(pn.x+pm.x) + bo4.x;
  float v1 = ev.y + a*(pn.y+pm.y) + bo4.y;
  float v2 = ev.z + a*(pn.z+pm.z) + bo4.z;
  float v3 = ev.w + a*(pn.w+pm.w) + bo4.w;
  float s = v0+v1+v2+v3;
#pragma unroll
  for(int off=1;off<64;off<<=1) s += __shfl_xor(s, off);
  float mean = s*(1.f/256.f);
  float c0f=v0-mean, c1f=v1-mean, c2f=v2-mean, c3f=v3-mean;
  float sq = c0f*c0f+c1f*c1f+c2f*c2f+c3f*c3f;
#pragma unroll
  for(int off=1;off<64;off<<=1) sq += __shfl_xor(sq, off);
  float rs = rsqrtf(sq*(1.f/256.f) + 1e-5f);
  float4 g = *(const float4*)(g2 + c0);
  float4 bb = *(const float4*)(b2 + c0);
  float4 o;
  o.x = c0f*rs*g.x+bb.x;
  o.y = c1f*rs*g.y+bb.y;
  o.z = c2f*rs*g.z+bb.z;
  o.w = c3f*rs*g.w+bb.w;
  *(float4*)(out + pair*256 + c0) = o;
}

// ---------------------------------------------------------------------------
extern "C" void kernel_launch(void* const* d_in, const int* in_sizes, int n_in,
                              void* d_out, int out_size, void* d_ws, size_t ws_size,
                              hipStream_t stream){
  (void)in_sizes; (void)n_in; (void)out_size; (void)ws_size;
  const float* node = (const float*)d_in[0];
  const float* edge = (const float*)d_in[1];
  const int*   adj  = (const int*)d_in[2];
  const float* Wn  = (const float*)d_in[3];
  const float* bn  = (const float*)d_in[4];
  const float* Wq  = (const float*)d_in[5];
  const float* bq  = (const float*)d_in[6];
  const float* Wk  = (const float*)d_in[7];
  const float* bk  = (const float*)d_in[8];
  const float* Wv  = (const float*)d_in[9];
  const float* bv  = (const float*)d_in[10];
  const float* Wep = (const float*)d_in[11];
  const float* bep = (const float*)d_in[12];
  const float* Weg = (const float*)d_in[13];
  const float* beg = (const float*)d_in[14];
  const float* Wo  = (const float*)d_in[15];
  const float* bo  = (const float*)d_in[16];
  const float* Weo = (const float*)d_in[17];
  const float* beo = (const float*)d_in[18];
  const float* g1  = (const float*)d_in[19];
  const float* b1  = (const float*)d_in[20];
  const float* g2  = (const float*)d_in[21];
  const float* b2  = (const float*)d_in[22];

  unsigned short* WcatT = (unsigned short*)d_ws;               // 512*256 bf16
  float* fws  = (float*)((char*)d_ws + (size_t)512*256*2);
  float* bcat = fws;                 // 512
  float* h    = bcat + 512;          // 131072
  float* Q    = h    + 131072;
  float* K    = Q    + 131072;
  float* V    = K    + 131072;
  float* attn = V    + 131072;       // 1048576 (edge_attn, then attn in place)
  float* am   = attn + 1048576;      // 131072
  float* P    = am   + 131072;       // 131072
  float* aout = P    + 131072;       // 131072

  float* out = (float*)d_out;

  k_build_w  <<<512, 256, 0, stream>>>(Wep, bep, Weg, beg, WcatT, bcat, am);
  k_gemm_qkv <<<5632, 256, 0, stream>>>(edge, WcatT, bcat, attn,
                                        node, Wn, bn, Wq, bq, Wk, bk, Wv, bv, h, Q, K, V);
  k_attn     <<<dim3(32,8,2), 256, 0, stream>>>(Q, K, V, adj, attn, aout, am);
  k_hout     <<<512, 256, 0, stream>>>(aout, h, Wo, bo, g1, b1, Weo, P, out);
  k_edge_out <<<32768, 256, 0, stream>>>(edge, am, P, beo, g2, b2, out + (size_t)BB*NN*HID);
}

// Round 13
// 388.515 us; speedup vs baseline: 1.0978x; 1.0978x over previous
//
#include <hip/hip_runtime.h>
#include <hip/hip_bf16.h>

#define BB 2
#define NN 256
#define HID 256
#define NH 8
#define HD 32
#define NPAIR (BB*NN*NN)   // 131072

typedef __attribute__((ext_vector_type(8))) short bf16x8;
typedef __attribute__((ext_vector_type(4))) float f32x4;

__device__ __forceinline__ unsigned short f2bf(float f){
  union{float f; unsigned int i;} v; v.f=f;
  unsigned int r = v.i + 0x7fffu + ((v.i>>16)&1u);
  return (unsigned short)(r>>16);
}

__device__ __forceinline__ float block_reduce_sum(float v, float* red){
  int t = threadIdx.x;
  red[t]=v; __syncthreads();
  for(int off=128; off>0; off>>=1){ if(t<off) red[t]+=red[t+off]; __syncthreads(); }
  float r = red[0]; __syncthreads();
  return r;
}

// ---------------------------------------------------------------------------
// K0: reordered bf16 weight WcatT[vcol][k] + bias bcat[vcol] (f32).
// Also zero-inits am (512 x 256 == NPAIR) for k_attn's atomic head-mean.
__global__ void k_build_w(const float* __restrict__ Wep,
                          const float* __restrict__ bep,
                          const float* __restrict__ Weg,
                          const float* __restrict__ beg,
                          unsigned short* __restrict__ WcatT,
                          float* __restrict__ bcat,
                          float* __restrict__ am){
  int vcol = blockIdx.x, k = threadIdx.x;
  am[(size_t)vcol*256 + k] = 0.f;
  int hv = vcol >> 6, wi = vcol & 63;
  int col = hv*32 + (wi & 31);
  const float* W = (wi < 32) ? Wep : Weg;
  WcatT[(size_t)vcol*256 + k] = f2bf(W[(size_t)k*256 + col]);
  if (k==0){
    const float* bb = (wi<32) ? bep : beg;
    bcat[vcol] = bb[col];
  }
}

// ---------------------------------------------------------------------------
// KF: FUSED nodeqkv + edge_gemm — R11-exact body (measured 115.5µs, best of
// 6 GEMM variants; R12's B-direct-from-L2 regressed to 153.7µs: L2 round-trips
// on the MFMA critical path, occupancy unchanged). GEMM ledger CLOSED:
// fused-cvt+Bs-LDS 115.5 | fat-tile 122 | dbuf 150 | B-direct 154 | prefetch 160.
__global__ __launch_bounds__(256) void k_gemm_qkv(
    const float* __restrict__ edge,            // [NPAIR][256] fp32
    const unsigned short* __restrict__ WcatT,  // [512][256] bf16
    const float* __restrict__ bcat,            // [512]
    float* __restrict__ edge_attn,             // [B*H][N*N]
    const float* __restrict__ node, const float* __restrict__ Wn,
    const float* __restrict__ bn,
    const float* __restrict__ Wq, const float* __restrict__ bq,
    const float* __restrict__ Wk, const float* __restrict__ bk,
    const float* __restrict__ Wv, const float* __restrict__ bv,
    float* __restrict__ h,
    float* __restrict__ Q, float* __restrict__ K, float* __restrict__ V)
{
  __shared__ __align__(16) short As[128][72];
  __shared__ __align__(16) short Bs[128][72];
  __shared__ float xs[128];
  __shared__ float hs[256];

  if (blockIdx.x < 1536){
    // ---- nodeqkv body (R10-exact): row x mat, bitwise-identical chains ----
    int row = blockIdx.x & 511, mat = blockIdx.x >> 9, c = threadIdx.x;
    if (c < 128) xs[c] = node[(size_t)row*128 + c];
    __syncthreads();
    float acc = bn[c];
#pragma unroll 16
    for (int k=0;k<128;k++) acc += xs[k]*Wn[(size_t)k*256+c];
    if (mat==0) h[(size_t)row*256+c] = acc;
    hs[c] = acc;
    __syncthreads();
    const float* W  = (mat==0)?Wq:((mat==1)?Wk:Wv);
    const float* bb = (mat==0)?bq:((mat==1)?bk:bv);
    float*       O  = (mat==0)?Q :((mat==1)?K :V );
    float a2 = bb[c];
#pragma unroll 16
    for (int k=0;k<256;k++) a2 += hs[k]*W[(size_t)k*256+c];
    O[(size_t)row*256+c] = a2;
    return;
  }

  // ---- gemm body (R6-exact inner loop, Bs LDS staging) ----
  int id = blockIdx.x - 1536;
  int bm = ((id>>5)<<3) | (id&7);
  int bv2 = (id>>3)&3;
  int tid = threadIdx.x;
  int w = tid>>6, lane = tid&63;
  int wr = w>>1, wc = w&1;
  int q = lane>>4, cl = lane&15;

  f32x4 acc[4][4];
#pragma unroll
  for(int i=0;i<4;i++)
#pragma unroll
    for(int j=0;j<4;j++) acc[i][j] = (f32x4){0.f,0.f,0.f,0.f};

  int r0 = tid>>4, c4 = tid&15;
  for(int kc=0;kc<4;kc++){
    int k0 = kc*64;
#pragma unroll
    for(int i=0;i<8;i++){
      int r = r0 + i*16;
      float4 f = *(const float4*)(edge + (size_t)(bm*128+r)*256 + k0 + c4*4);
      __hip_bfloat162 lo = __float22bfloat162_rn(make_float2(f.x,f.y));
      __hip_bfloat162 hi = __float22bfloat162_rn(make_float2(f.z,f.w));
      uint2 u; u.x = *(unsigned int*)&lo; u.y = *(unsigned int*)&hi;
      *(uint2*)(&As[r][c4*4]) = u;
    }
#pragma unroll
    for(int i=0;i<4;i++){
      int g = tid + i*256; int r = g>>3, s8 = g&7;
      *(uint4*)(&Bs[r][s8*8]) = *(const uint4*)(WcatT + (size_t)(bv2*128+r)*256 + k0 + s8*8);
    }
    __syncthreads();
#pragma unroll
    for(int ks=0;ks<2;ks++){
      int kb = ks*32 + q*8;
      bf16x8 a[4], bfr[4];
#pragma unroll
      for(int tm=0;tm<4;tm++) a[tm]  = *(const bf16x8*)(&As[wr*64+tm*16+cl][kb]);
#pragma unroll
      for(int tn=0;tn<4;tn++) bfr[tn]= *(const bf16x8*)(&Bs[wc*64+tn*16+cl][kb]);
#pragma unroll
      for(int tm=0;tm<4;tm++)
#pragma unroll
        for(int tn=0;tn<4;tn++)
          acc[tm][tn] = __builtin_amdgcn_mfma_f32_16x16x32_bf16(a[tm], bfr[tn], acc[tm][tn], 0, 0, 0);
    }
    __syncthreads();
  }

  int head = bv2*2 + wc;
  float bias[4];
#pragma unroll
  for(int tn=0;tn<4;tn++) bias[tn] = bcat[bv2*128 + wc*64 + tn*16 + cl];

#pragma unroll
  for(int tm=0;tm<4;tm++){
    float s[4] = {0.f,0.f,0.f,0.f};
#pragma unroll
    for(int tn=0;tn<2;tn++){
#pragma unroll
      for(int r=0;r<4;r++){
        float eh = acc[tm][tn][r]   + bias[tn];
        float gg = acc[tm][tn+2][r] + bias[tn+2];
        s[r] += eh * (1.f/(1.f + __expf(-gg)));
      }
    }
#pragma unroll
    for(int off=1;off<16;off<<=1){
#pragma unroll
      for(int r=0;r<4;r++) s[r] += __shfl_xor(s[r], off);
    }
    if (cl==0){
      int R = bm*128 + wr*64 + tm*16 + q*4;
      int b = R>>16, rem = R&65535;
#pragma unroll
      for(int r=0;r<4;r++)
        edge_attn[(size_t)(b*NH+head)*65536 + rem + r] = s[r];
    }
  }
}

// ---------------------------------------------------------------------------
// KC: attention. Pad 33 (R12): QK banks = (33m+4i)%32 = (m+4i)%32 ->
// conflict-free across lanes; R10's 36 gave 4(m+i)%32 = 8-way. Block stages
// K/V once, 8 query rows (2 reps x 4 waves); atomic head-mean (R8).
__global__ __launch_bounds__(256) void k_attn(
    const float* __restrict__ Q, const float* __restrict__ Km,
    const float* __restrict__ V, const int* __restrict__ adj,
    float* __restrict__ attn, float* __restrict__ attn_out,
    float* __restrict__ am){
  __shared__ float Ks[256][33];
  __shared__ float Vs[256][33];
  __shared__ float arow[4][264];
  int b = blockIdx.z, hh = blockIdx.y;
  int t = threadIdx.x;
  int mrow = t>>3, dg = (t&7)*4;
#pragma unroll
  for(int it=0; it<8; it++){
    int m = mrow + it*32;
    size_t base = ((size_t)(b*NN+m))*HID + hh*HD + dg;
    *(float4*)&Ks[m][dg] = *(const float4*)(Km + base);
    *(float4*)&Vs[m][dg] = *(const float4*)(V + base);
  }
  __syncthreads();

  int w = t>>6, lane = t&63;
  int mc = lane>>3, dg4 = (lane&7)*4;

  for (int rep=0; rep<2; ++rep){
    int n = blockIdx.x*8 + rep*4 + w;
    const float* qp = Q + ((size_t)(b*NN+n))*HID + hh*HD;
    float4 q[8];
#pragma unroll
    for(int i=0;i<8;i++) q[i] = *(const float4*)(qp + i*4);

    size_t eoff = ((size_t)((b*NH+hh)*NN + n))*NN;
    const int* abase = adj + ((size_t)(b*NN+n))*NN;
    float sc[4];
#pragma unroll
    for(int j=0;j<4;j++){
      int m = lane + j*64;
      float d = 0.f;
#pragma unroll
      for(int i=0;i<8;i++){
        float4 kk = *(float4*)&Ks[m][i*4];
        d += q[i].x*kk.x + q[i].y*kk.y + q[i].z*kk.z + q[i].w*kk.w;
      }
      float s = d*0.17677669529663687f + attn[eoff + m];
      if (abase[m]==0) s = -1e9f;
      sc[j] = s;
    }
    float mx = fmaxf(fmaxf(sc[0],sc[1]),fmaxf(sc[2],sc[3]));
#pragma unroll
    for(int off=1;off<64;off<<=1) mx = fmaxf(mx, __shfl_xor(mx, off));
    float e[4], sum = 0.f;
#pragma unroll
    for(int j=0;j<4;j++){ e[j] = __expf(sc[j]-mx); sum += e[j]; }
#pragma unroll
    for(int off=1;off<64;off<<=1) sum += __shfl_xor(sum, off);
    float inv = 1.f/sum;
    float* amrow = am + (size_t)b*65536 + n*256;
#pragma unroll
    for(int j=0;j<4;j++){
      int m = lane + j*64;
      float a = e[j]*inv;
      attn[eoff + m] = a;
      arow[w][m + (m>>5)] = a;   // stride-33 chunks: conflict-free broadcast
      atomicAdd(amrow + m, a*0.125f);
    }
    float4 o = {0.f,0.f,0.f,0.f};
#pragma unroll
    for(int j=0;j<32;j++){
      int m = mc*32 + j;
      float a = arow[w][m + (m>>5)];
      float4 v = *(float4*)&Vs[m][dg4];
      o.x += a*v.x; o.y += a*v.y; o.z += a*v.z; o.w += a*v.w;
    }
#pragma unroll
    for(int off=8; off<64; off<<=1){
      o.x += __shfl_xor(o.x, off); o.y += __shfl_xor(o.y, off);
      o.z += __shfl_xor(o.z, off); o.w += __shfl_xor(o.w, off);
    }
    if (mc==0)
      *(float4*)(attn_out + ((size_t)(b*NN+n))*HID + hh*HD + dg4) = o;
  }
}

// ---------------------------------------------------------------------------
// KD: fused h_out = LN(h + attn_out@Wo + bo) -> d_out ; P = h_out@Weo
__global__ __launch_bounds__(256) void k_hout(
    const float* __restrict__ attn_out, const float* __restrict__ hres,
    const float* __restrict__ Wo, const float* __restrict__ bo,
    const float* __restrict__ g1, const float* __restrict__ b1,
    const float* __restrict__ Weo,
    float* __restrict__ P, float* __restrict__ out){
  __shared__ float xs[256]; __shared__ float red[256]; __shared__ float hs[256];
  int row = blockIdx.x, c = threadIdx.x;
  xs[c] = attn_out[(size_t)row*256 + c];
  __syncthreads();
  float acc = bo[c];
#pragma unroll 16
  for(int k=0;k<256;k++) acc += xs[k]*Wo[(size_t)k*256+c];
  float val = hres[(size_t)row*256+c] + acc;
  float mean = block_reduce_sum(val, red) * (1.f/256.f);
  float ctr = val - mean;
  float var = block_reduce_sum(ctr*ctr, red) * (1.f/256.f);
  float o = ctr * rsqrtf(var + 1e-5f) * g1[c] + b1[c];
  out[(size_t)row*256+c] = o;
  hs[c] = o;
  __syncthreads();
  float accP = 0.f;
#pragma unroll 16
  for(int k=0;k<256;k++) accP += hs[k]*Weo[(size_t)k*256+c];
  P[(size_t)row*256+c] = accP;
}

// ---------------------------------------------------------------------------
// KE: edge_out = LN(edge + attn_mean*0.5*(P[n]+P[m]) + beo). One wave per pair.
__global__ __launch_bounds__(256) void k_edge_out(
    const float* __restrict__ ef, const float* __restrict__ am,
    const float* __restrict__ P, const float* __restrict__ beo,
    const float* __restrict__ g2, const float* __restrict__ b2,
    float* __restrict__ out){
  int w = threadIdx.x>>6, lane = threadIdx.x&63;
  size_t pair = (size_t)blockIdx.x*4 + w;
  int b = (int)(pair>>16); int rem = (int)(pair&65535);
  int n = rem>>8, m = rem&255;
  float a = am[pair]*0.5f;
  const float* Pn = P + (size_t)(b*NN+n)*HID;
  const float* Pm = P + (size_t)(b*NN+m)*HID;
  int c0 = lane*4;
  float4 ev = *(const float4*)(ef + pair*256 + c0);
  float4 pn = *(const float4*)(Pn + c0);
  float4 pm = *(const float4*)(Pm + c0);
  float4 bo4 = *(const float4*)(beo + c0);
  float v0 = ev.x + a*(pn.x+pm.x) + bo4.x;
  float v1 = ev.y + a*(pn.y+pm.y) + bo4.y;
  float v2 = ev.z + a*(pn.z+pm.z) + bo4.z;
  float v3 = ev.w + a*(pn.w+pm.w) + bo4.w;
  float s = v0+v1+v2+v3;
#pragma unroll
  for(int off=1;off<64;off<<=1) s += __shfl_xor(s, off);
  float mean = s*(1.f/256.f);
  float c0f=v0-mean, c1f=v1-mean, c2f=v2-mean, c3f=v3-mean;
  float sq = c0f*c0f+c1f*c1f+c2f*c2f+c3f*c3f;
#pragma unroll
  for(int off=1;off<64;off<<=1) sq += __shfl_xor(sq, off);
  float rs = rsqrtf(sq*(1.f/256.f) + 1e-5f);
  float4 g = *(const float4*)(g2 + c0);
  float4 bb = *(const float4*)(b2 + c0);
  float4 o;
  o.x = c0f*rs*g.x+bb.x;
  o.y = c1f*rs*g.y+bb.y;
  o.z = c2f*rs*g.z+bb.z;
  o.w = c3f*rs*g.w+bb.w;
  *(float4*)(out + pair*256 + c0) = o;
}

// ---------------------------------------------------------------------------
extern "C" void kernel_launch(void* const* d_in, const int* in_sizes, int n_in,
                              void* d_out, int out_size, void* d_ws, size_t ws_size,
                              hipStream_t stream){
  (void)in_sizes; (void)n_in; (void)out_size; (void)ws_size;
  const float* node = (const float*)d_in[0];
  const float* edge = (const float*)d_in[1];
  const int*   adj  = (const int*)d_in[2];
  const float* Wn  = (const float*)d_in[3];
  const float* bn  = (const float*)d_in[4];
  const float* Wq  = (const float*)d_in[5];
  const float* bq  = (const float*)d_in[6];
  const float* Wk  = (const float*)d_in[7];
  const float* bk  = (const float*)d_in[8];
  const float* Wv  = (const float*)d_in[9];
  const float* bv  = (const float*)d_in[10];
  const float* Wep = (const float*)d_in[11];
  const float* bep = (const float*)d_in[12];
  const float* Weg = (const float*)d_in[13];
  const float* beg = (const float*)d_in[14];
  const float* Wo  = (const float*)d_in[15];
  const float* bo  = (const float*)d_in[16];
  const float* Weo = (const float*)d_in[17];
  const float* beo = (const float*)d_in[18];
  const float* g1  = (const float*)d_in[19];
  const float* b1  = (const float*)d_in[20];
  const float* g2  = (const float*)d_in[21];
  const float* b2  = (const float*)d_in[22];

  unsigned short* WcatT = (unsigned short*)d_ws;               // 512*256 bf16
  float* fws  = (float*)((char*)d_ws + (size_t)512*256*2);
  float* bcat = fws;                 // 512
  float* h    = bcat + 512;          // 131072
  float* Q    = h    + 131072;
  float* K    = Q    + 131072;
  float* V    = K    + 131072;
  float* attn = V    + 131072;       // 1048576 (edge_attn, then attn in place)
  float* am   = attn + 1048576;      // 131072
  float* P    = am   + 131072;       // 131072
  float* aout = P    + 131072;       // 131072

  float* out = (float*)d_out;

  k_build_w  <<<512, 256, 0, stream>>>(Wep, bep, Weg, beg, WcatT, bcat, am);
  k_gemm_qkv <<<5632, 256, 0, stream>>>(edge, WcatT, bcat, attn,
                                        node, Wn, bn, Wq, bq, Wk, bk, Wv, bv, h, Q, K, V);
  k_attn     <<<dim3(32,8,2), 256, 0, stream>>>(Q, K, V, adj, attn, aout, am);
  k_hout     <<<512, 256, 0, stream>>>(aout, h, Wo, bo, g1, b1, Weo, P, out);
  k_edge_out <<<32768, 256, 0, stream>>>(edge, am, P, beo, g2, b2, out + (size_t)BB*NN*HID);
}